// Round 2
// baseline (2177.128 us; speedup 1.0000x reference)
//
#include <hip/hip_runtime.h>
#include <hip/hip_bf16.h>
#include <cmath>

#define NNODES 100000
#define NEDGES 1600000

// ---------------- degree / norm precompute ----------------

__global__ void deg_init(float* __restrict__ deg, int n) {
    int i = blockIdx.x * 256 + threadIdx.x;
    if (i < n) deg[i] = 1.0f;   // self-loop
}

__global__ void deg_count(const int* __restrict__ dst, float* __restrict__ deg, int E) {
    int e = blockIdx.x * 256 + threadIdx.x;
    if (e < E) atomicAdd(&deg[dst[e]], 1.0f);
}

__global__ void deg_rsqrt(float* __restrict__ d, int n) {
    int i = blockIdx.x * 256 + threadIdx.x;
    if (i < n) d[i] = rsqrtf(d[i]);
}

__global__ void make_norm(const int* __restrict__ src, const int* __restrict__ dst,
                          const float* __restrict__ dinv, float* __restrict__ norm, int E) {
    int e = blockIdx.x * 256 + threadIdx.x;
    if (e < E) norm[e] = dinv[src[e]] * dinv[dst[e]];
}

// ---------------- GEMM: C[M,TN] = A[M,K] @ W[K,TN], optional fused (A+bias)->relu on load ----
// 256 threads as 16x16; each thread computes a 4 x (TN/16) register microtile.

template<int TN, int KC, bool RELU_BIAS>
__global__ __launch_bounds__(256) void gemm_bias(
    const float* __restrict__ A, const float* __restrict__ W,
    const float* __restrict__ bias, float* __restrict__ C,
    int M, int K)
{
    constexpr int TR = 64;
    constexpr int CPT = TN / 16;
    __shared__ float sA[TR][KC + 1];
    __shared__ float sW[KC][TN];
    const int tx = threadIdx.x & 15;
    const int ty = threadIdx.x >> 4;
    const int row0 = blockIdx.x * TR;

    float acc[4][CPT];
    #pragma unroll
    for (int i = 0; i < 4; i++)
        #pragma unroll
        for (int j = 0; j < CPT; j++) acc[i][j] = 0.0f;

    for (int kc = 0; kc < K; kc += KC) {
        const int kend = (K - kc < KC) ? (K - kc) : KC;
        // stage A tile (coalesced along k)
        for (int idx = threadIdx.x; idx < TR * KC; idx += 256) {
            int r = idx / KC, k = idx % KC;
            int row = row0 + r;
            float v = 0.0f;
            if (row < M && k < kend) {
                v = A[(long)row * K + kc + k];
                if (RELU_BIAS) v = fmaxf(v + bias[kc + k], 0.0f);
            }
            sA[r][k] = v;
        }
        // stage W tile (coalesced along columns)
        for (int idx = threadIdx.x; idx < KC * TN; idx += 256) {
            int k = idx / TN, c = idx % TN;
            sW[k][c] = (k < kend) ? W[(long)(kc + k) * TN + c] : 0.0f;
        }
        __syncthreads();
        #pragma unroll 2
        for (int k = 0; k < KC; ++k) {
            float ar[4];
            #pragma unroll
            for (int i = 0; i < 4; i++) ar[i] = sA[ty + 16 * i][k];
            float wr[CPT];
            #pragma unroll
            for (int j = 0; j < CPT; j++) wr[j] = sW[k][tx + 16 * j];
            #pragma unroll
            for (int i = 0; i < 4; i++)
                #pragma unroll
                for (int j = 0; j < CPT; j++) acc[i][j] += ar[i] * wr[j];
        }
        __syncthreads();
    }
    #pragma unroll
    for (int i = 0; i < 4; i++) {
        int row = row0 + ty + 16 * i;
        if (row < M) {
            #pragma unroll
            for (int j = 0; j < CPT; j++)
                C[(long)row * TN + tx + 16 * j] = acc[i][j];
        }
    }
}

// ---------------- small GEMM for layer 3: K=64, N=40, fused relu(A+b2) ----------------

__global__ __launch_bounds__(256) void gemm_n40(
    const float* __restrict__ A, const float* __restrict__ W,
    const float* __restrict__ bias, float* __restrict__ C, int M)
{
    __shared__ float sA[32][65];
    __shared__ float sW[64][40];
    const int row0 = blockIdx.x * 32;
    for (int idx = threadIdx.x; idx < 64 * 40; idx += 256)
        sW[idx / 40][idx % 40] = W[idx];
    for (int idx = threadIdx.x; idx < 32 * 64; idx += 256) {
        int r = idx >> 6, k = idx & 63;
        int row = row0 + r;
        float v = 0.0f;
        if (row < M) v = fmaxf(A[(long)row * 64 + k] + bias[k], 0.0f);
        sA[r][k] = v;
    }
    __syncthreads();
    float acc[5] = {0, 0, 0, 0, 0};
    int rr[5], cc[5];
    #pragma unroll
    for (int j = 0; j < 5; j++) {
        int o = threadIdx.x + 256 * j;
        rr[j] = o / 40; cc[j] = o % 40;
    }
    for (int k = 0; k < 64; k++) {
        #pragma unroll
        for (int j = 0; j < 5; j++) acc[j] += sA[rr[j]][k] * sW[k][cc[j]];
    }
    #pragma unroll
    for (int j = 0; j < 5; j++) {
        int row = row0 + rr[j];
        if (row < M) C[(long)row * 40 + cc[j]] = acc[j];
    }
}

// ---------------- aggregation: self-loop init + edge scatter ----------------

template<int N>
__global__ void self_init(const float* __restrict__ h, const float* __restrict__ dinv,
                          float* __restrict__ out, unsigned total) {
    unsigned idx = blockIdx.x * 256u + threadIdx.x;
    if (idx < total) {
        unsigned i = idx / N;
        float di = dinv[i];
        out[idx] = di * di * h[idx];
    }
}

template<int N>
__global__ void scatter_edges(const float* __restrict__ h, const int* __restrict__ src,
                              const int* __restrict__ dst, const float* __restrict__ norm,
                              float* __restrict__ out, unsigned total) {
    unsigned idx = blockIdx.x * 256u + threadIdx.x;
    if (idx < total) {
        unsigned e = idx / N;
        unsigned c = idx % N;
        unsigned s = (unsigned)src[e], d = (unsigned)dst[e];
        atomicAdd(&out[d * N + c], norm[e] * h[s * N + c]);
    }
}

// ---------------- log_softmax over rows of 40 (one wave per row), in-place safe ----------------

__global__ __launch_bounds__(256) void logsoftmax40(const float* __restrict__ h,
                                                    const float* __restrict__ bias,
                                                    float* __restrict__ out, int n) {
    int wave = (blockIdx.x * 256 + threadIdx.x) >> 6;
    int lane = threadIdx.x & 63;
    if (wave >= n) return;
    float x = 0.0f, v = -INFINITY;
    if (lane < 40) { x = h[(long)wave * 40 + lane] + bias[lane]; v = x; }
    #pragma unroll
    for (int off = 32; off; off >>= 1) v = fmaxf(v, __shfl_xor(v, off, 64));
    float ex = (lane < 40) ? expf(x - v) : 0.0f;
    float s = ex;
    #pragma unroll
    for (int off = 32; off; off >>= 1) s += __shfl_xor(s, off, 64);
    if (lane < 40) out[(long)wave * 40 + lane] = x - v - logf(s);
}

// ---------------- launch ----------------

extern "C" void kernel_launch(void* const* d_in, const int* in_sizes, int n_in,
                              void* d_out, int out_size, void* d_ws, size_t ws_size,
                              hipStream_t stream) {
    const float* x  = (const float*)d_in[0];
    const int*   ei = (const int*)d_in[1];      // int32 per harness contract (ref int64 -> int)
    const float* W1 = (const float*)d_in[2];
    const float* b1 = (const float*)d_in[3];
    const float* W2 = (const float*)d_in[4];
    const float* b2 = (const float*)d_in[5];
    const float* W4 = (const float*)d_in[6];
    const float* b4 = (const float*)d_in[7];
    float* out = (float*)d_out;
    float* ws  = (float*)d_ws;

    const int N = NNODES, E = NEDGES;
    const int* src = ei;
    const int* dst = ei + E;

    // workspace layout (floats), with reuse:
    float* dinv = ws;                  // 100000
    float* norm = ws + 100000;         // 1.6M
    float* P    = ws + 1700000;        // 12.8M region
    float* Q    = ws + 14500000;       // 12.8M region
    float* h1 = P;                     // [N,128]
    float* a1 = Q;                     // [N,128] raw agg (bias/relu fused downstream)
    float* h2 = P;                     // [N,64]  (h1 dead)
    float* a2 = P + 6400000;           // [N,64]
    float* h3 = Q;                     // [N,40]  (a1 dead)
    float* a3 = out;                   // [N,40]  accumulate directly in d_out; logsoftmax in-place

    // degree / norm
    deg_init<<<(N + 255) / 256, 256, 0, stream>>>(dinv, N);
    deg_count<<<(E + 255) / 256, 256, 0, stream>>>(dst, dinv, E);
    deg_rsqrt<<<(N + 255) / 256, 256, 0, stream>>>(dinv, N);
    make_norm<<<(E + 255) / 256, 256, 0, stream>>>(src, dst, dinv, norm, E);

    // layer 1: h1 = x @ W1 ; a1 = Ahat * h1
    gemm_bias<128, 50, false><<<(N + 63) / 64, 256, 0, stream>>>(x, W1, nullptr, h1, N, 500);
    {
        unsigned tot = (unsigned)N * 128u;
        self_init<128><<<(tot + 255) / 256, 256, 0, stream>>>(h1, dinv, a1, tot);
        unsigned tote = (unsigned)E * 128u;
        scatter_edges<128><<<(tote + 255) / 256, 256, 0, stream>>>(h1, src, dst, norm, a1, tote);
    }

    // layer 2: h2 = relu(a1 + b1) @ W2 ; a2 = Ahat * h2
    gemm_bias<64, 64, true><<<(N + 63) / 64, 256, 0, stream>>>(a1, W2, b1, h2, N, 128);
    {
        unsigned tot = (unsigned)N * 64u;
        self_init<64><<<(tot + 255) / 256, 256, 0, stream>>>(h2, dinv, a2, tot);
        unsigned tote = (unsigned)E * 64u;
        scatter_edges<64><<<(tote + 255) / 256, 256, 0, stream>>>(h2, src, dst, norm, a2, tote);
    }

    // layer 3: h3 = relu(a2 + b2) @ W4 ; a3 = Ahat * h3 (into d_out)
    gemm_n40<<<(N + 31) / 32, 256, 0, stream>>>(a2, W4, b2, h3, N);
    {
        unsigned tot = (unsigned)N * 40u;
        self_init<40><<<(tot + 255) / 256, 256, 0, stream>>>(h3, dinv, a3, tot);
        unsigned tote = (unsigned)E * 40u;
        scatter_edges<40><<<(tote + 255) / 256, 256, 0, stream>>>(h3, src, dst, norm, a3, tote);
    }

    // log_softmax(a3 + b4) in-place into out
    logsoftmax40<<<(N * 64 + 255) / 256, 256, 0, stream>>>(a3, b4, out, N);
}

// Round 3
// 1504.235 us; speedup vs baseline: 1.4473x; 1.4473x over previous
//
#include <hip/hip_runtime.h>
#include <hip/hip_bf16.h>
#include <cmath>

#define NNODES 100000
#define NEDGES 1600000
#define SCAN_B 1024

// ---------------- CSR build ----------------

__global__ void zero_deg(int* __restrict__ deg, int n) {
    int i = blockIdx.x * 256 + threadIdx.x;
    if (i < n) deg[i] = 0;
}

__global__ void count_deg(const int* __restrict__ dst, int* __restrict__ deg, int E) {
    int e = blockIdx.x * 256 + threadIdx.x;
    if (e < E) atomicAdd(&deg[dst[e]], 1);
}

__global__ void calc_dinv(const int* __restrict__ deg, float* __restrict__ dinv, int n) {
    int i = blockIdx.x * 256 + threadIdx.x;
    if (i < n) dinv[i] = rsqrtf(1.0f + (float)deg[i]);   // +1 self-loop
}

// exclusive scan of deg -> pos, per-block, with block sums
__global__ __launch_bounds__(SCAN_B) void scan_block(const int* __restrict__ deg,
                                                     int* __restrict__ pos,
                                                     int* __restrict__ bsums, int n) {
    __shared__ int s[SCAN_B];
    int tid = threadIdx.x;
    int gid = blockIdx.x * SCAN_B + tid;
    int v = (gid < n) ? deg[gid] : 0;
    s[tid] = v;
    __syncthreads();
    for (int off = 1; off < SCAN_B; off <<= 1) {
        int t = (tid >= off) ? s[tid - off] : 0;
        __syncthreads();
        s[tid] += t;
        __syncthreads();
    }
    if (gid < n) pos[gid] = s[tid] - v;          // exclusive
    if (tid == SCAN_B - 1) bsums[blockIdx.x] = s[tid];
}

__global__ __launch_bounds__(128) void scan_sums(int* __restrict__ bsums, int nb) {
    __shared__ int s[128];
    int tid = threadIdx.x;
    int v = (tid < nb) ? bsums[tid] : 0;
    s[tid] = v;
    __syncthreads();
    for (int off = 1; off < 128; off <<= 1) {
        int t = (tid >= off) ? s[tid - off] : 0;
        __syncthreads();
        s[tid] += t;
        __syncthreads();
    }
    if (tid < nb) bsums[tid] = s[tid] - v;       // exclusive
}

__global__ __launch_bounds__(SCAN_B) void add_off(int* __restrict__ pos,
                                                  const int* __restrict__ bsums, int n) {
    int gid = blockIdx.x * SCAN_B + threadIdx.x;
    if (gid < n) pos[gid] += bsums[blockIdx.x];
}

// fill CSR; pos[] is mutated into end[] (pos[i] becomes start[i]+deg[i] == start of i+1)
__global__ void csr_fill(const int* __restrict__ src, const int* __restrict__ dst,
                         int* __restrict__ pos, int* __restrict__ csr_src, int E) {
    int e = blockIdx.x * 256 + threadIdx.x;
    if (e < E) {
        int slot = atomicAdd(&pos[dst[e]], 1);
        csr_src[slot] = src[e];
    }
}

// ---------------- GEMM: C[M,TN] = A[M,K] @ W[K,TN], optional fused (A+bias)->relu on load ----

template<int TN, int KC, bool RELU_BIAS>
__global__ __launch_bounds__(256) void gemm_bias(
    const float* __restrict__ A, const float* __restrict__ W,
    const float* __restrict__ bias, float* __restrict__ C,
    int M, int K)
{
    constexpr int TR = 64;
    constexpr int CPT = TN / 16;
    __shared__ float sA[TR][KC + 1];
    __shared__ float sW[KC][TN];
    const int tx = threadIdx.x & 15;
    const int ty = threadIdx.x >> 4;
    const int row0 = blockIdx.x * TR;

    float acc[4][CPT];
    #pragma unroll
    for (int i = 0; i < 4; i++)
        #pragma unroll
        for (int j = 0; j < CPT; j++) acc[i][j] = 0.0f;

    for (int kc = 0; kc < K; kc += KC) {
        const int kend = (K - kc < KC) ? (K - kc) : KC;
        for (int idx = threadIdx.x; idx < TR * KC; idx += 256) {
            int r = idx / KC, k = idx % KC;
            int row = row0 + r;
            float v = 0.0f;
            if (row < M && k < kend) {
                v = A[(long)row * K + kc + k];
                if (RELU_BIAS) v = fmaxf(v + bias[kc + k], 0.0f);
            }
            sA[r][k] = v;
        }
        for (int idx = threadIdx.x; idx < KC * TN; idx += 256) {
            int k = idx / TN, c = idx % TN;
            sW[k][c] = (k < kend) ? W[(long)(kc + k) * TN + c] : 0.0f;
        }
        __syncthreads();
        #pragma unroll 2
        for (int k = 0; k < KC; ++k) {
            float ar[4];
            #pragma unroll
            for (int i = 0; i < 4; i++) ar[i] = sA[ty + 16 * i][k];
            float wr[CPT];
            #pragma unroll
            for (int j = 0; j < CPT; j++) wr[j] = sW[k][tx + 16 * j];
            #pragma unroll
            for (int i = 0; i < 4; i++)
                #pragma unroll
                for (int j = 0; j < CPT; j++) acc[i][j] += ar[i] * wr[j];
        }
        __syncthreads();
    }
    #pragma unroll
    for (int i = 0; i < 4; i++) {
        int row = row0 + ty + 16 * i;
        if (row < M) {
            #pragma unroll
            for (int j = 0; j < CPT; j++)
                C[(long)row * TN + tx + 16 * j] = acc[i][j];
        }
    }
}

// ---------------- small GEMM for layer 3: K=64, N=40, fused relu(A+b2) ----------------

__global__ __launch_bounds__(256) void gemm_n40(
    const float* __restrict__ A, const float* __restrict__ W,
    const float* __restrict__ bias, float* __restrict__ C, int M)
{
    __shared__ float sA[32][65];
    __shared__ float sW[64][40];
    const int row0 = blockIdx.x * 32;
    for (int idx = threadIdx.x; idx < 64 * 40; idx += 256)
        sW[idx / 40][idx % 40] = W[idx];
    for (int idx = threadIdx.x; idx < 32 * 64; idx += 256) {
        int r = idx >> 6, k = idx & 63;
        int row = row0 + r;
        float v = 0.0f;
        if (row < M) v = fmaxf(A[(long)row * 64 + k] + bias[k], 0.0f);
        sA[r][k] = v;
    }
    __syncthreads();
    float acc[5] = {0, 0, 0, 0, 0};
    int rr[5], cc[5];
    #pragma unroll
    for (int j = 0; j < 5; j++) {
        int o = threadIdx.x + 256 * j;
        rr[j] = o / 40; cc[j] = o % 40;
    }
    for (int k = 0; k < 64; k++) {
        #pragma unroll
        for (int j = 0; j < 5; j++) acc[j] += sA[rr[j]][k] * sW[k][cc[j]];
    }
    #pragma unroll
    for (int j = 0; j < 5; j++) {
        int row = row0 + rr[j];
        if (row < M) C[(long)row * 40 + cc[j]] = acc[j];
    }
}

// ---------------- CSR gather aggregation: out[i] = dinv[i]*(dinv[i]*h[i] + sum dinv[s]*h[s]) ----

template<int F>
__global__ __launch_bounds__(256) void gather_agg(
    const float* __restrict__ h, const float* __restrict__ dinv,
    const int* __restrict__ pos, const int* __restrict__ csr_src,
    float* __restrict__ out, int n)
{
    unsigned t = blockIdx.x * 256u + threadIdx.x;
    unsigned node = t / F;
    unsigned c = t - node * F;
    if (node >= (unsigned)n) return;
    int e0 = node ? pos[node - 1] : 0;   // pos was mutated into end[]; end[i-1] == start[i]
    int e1 = pos[node];
    float di = dinv[node];
    float acc = di * h[(size_t)node * F + c];
    int s = (e0 < e1) ? csr_src[e0] : 0;
    for (int j = e0; j < e1; j++) {
        int snxt = (j + 1 < e1) ? csr_src[j + 1] : 0;   // prefetch next src
        acc += dinv[s] * h[(size_t)s * F + c];
        s = snxt;
    }
    out[(size_t)node * F + c] = di * acc;
}

// ---------------- log_softmax over rows of 40 (one wave per row), in-place safe ----------------

__global__ __launch_bounds__(256) void logsoftmax40(const float* __restrict__ h,
                                                    const float* __restrict__ bias,
                                                    float* __restrict__ out, int n) {
    int wave = (blockIdx.x * 256 + threadIdx.x) >> 6;
    int lane = threadIdx.x & 63;
    if (wave >= n) return;
    float x = 0.0f, v = -INFINITY;
    if (lane < 40) { x = h[(long)wave * 40 + lane] + bias[lane]; v = x; }
    #pragma unroll
    for (int off = 32; off; off >>= 1) v = fmaxf(v, __shfl_xor(v, off, 64));
    float ex = (lane < 40) ? expf(x - v) : 0.0f;
    float s = ex;
    #pragma unroll
    for (int off = 32; off; off >>= 1) s += __shfl_xor(s, off, 64);
    if (lane < 40) out[(long)wave * 40 + lane] = x - v - logf(s);
}

// ---------------- launch ----------------

extern "C" void kernel_launch(void* const* d_in, const int* in_sizes, int n_in,
                              void* d_out, int out_size, void* d_ws, size_t ws_size,
                              hipStream_t stream) {
    const float* x  = (const float*)d_in[0];
    const int*   ei = (const int*)d_in[1];      // int32 per harness contract
    const float* W1 = (const float*)d_in[2];
    const float* b1 = (const float*)d_in[3];
    const float* W2 = (const float*)d_in[4];
    const float* b2 = (const float*)d_in[5];
    const float* W4 = (const float*)d_in[6];
    const float* b4 = (const float*)d_in[7];
    float* out = (float*)d_out;
    float* ws  = (float*)d_ws;

    const int N = NNODES, E = NEDGES;
    const int* src = ei;
    const int* dst = ei + E;

    // workspace layout (floats): total ~27.5M floats (~110 MB)
    float* dinv    = ws;                     // [0, 100k)
    int*   deg     = (int*)(ws + 100000);    // [100k, 200k)
    int*   pos     = (int*)(ws + 200000);    // [200k, 300k)
    int*   bsums   = (int*)(ws + 300000);    // [300k, 300128)
    int*   csr_src = (int*)(ws + 300200);    // [300.2k, 1900.2k)
    float* P       = ws + 1900200;           // 12.8M region
    float* Q       = ws + 14700200;          // 12.8M region
    float* h1 = P;                           // [N,128]
    float* a1 = Q;                           // [N,128]
    float* h2 = P;                           // [N,64]  (h1 dead)
    float* a2 = P + 6400000;                 // [N,64]
    float* h3 = Q;                           // [N,40]  (a1 dead)
    float* a3 = out;                         // [N,40]  -> logsoftmax in place

    const int nscan = (N + SCAN_B - 1) / SCAN_B;   // 98

    // ---- CSR build ----
    zero_deg<<<(N + 255) / 256, 256, 0, stream>>>(deg, N);
    count_deg<<<(E + 255) / 256, 256, 0, stream>>>(dst, deg, E);
    calc_dinv<<<(N + 255) / 256, 256, 0, stream>>>(deg, dinv, N);
    scan_block<<<nscan, SCAN_B, 0, stream>>>(deg, pos, bsums, N);
    scan_sums<<<1, 128, 0, stream>>>(bsums, nscan);
    add_off<<<nscan, SCAN_B, 0, stream>>>(pos, bsums, N);
    csr_fill<<<(E + 255) / 256, 256, 0, stream>>>(src, dst, pos, csr_src, E);

    // ---- layer 1: h1 = x @ W1 ; a1 = Ahat h1 ----
    gemm_bias<128, 50, false><<<(N + 63) / 64, 256, 0, stream>>>(x, W1, nullptr, h1, N, 500);
    {
        unsigned tot = (unsigned)N * 128u;
        gather_agg<128><<<(tot + 255) / 256, 256, 0, stream>>>(h1, dinv, pos, csr_src, a1, N);
    }

    // ---- layer 2: h2 = relu(a1 + b1) @ W2 ; a2 = Ahat h2 ----
    gemm_bias<64, 64, true><<<(N + 63) / 64, 256, 0, stream>>>(a1, W2, b1, h2, N, 128);
    {
        unsigned tot = (unsigned)N * 64u;
        gather_agg<64><<<(tot + 255) / 256, 256, 0, stream>>>(h2, dinv, pos, csr_src, a2, N);
    }

    // ---- layer 3: h3 = relu(a2 + b2) @ W4 ; a3 = Ahat h3 (into d_out) ----
    gemm_n40<<<(N + 31) / 32, 256, 0, stream>>>(a2, W4, b2, h3, N);
    {
        unsigned tot = (unsigned)N * 40u;
        gather_agg<40><<<(tot + 255) / 256, 256, 0, stream>>>(h3, dinv, pos, csr_src, a3, N);
    }

    // ---- log_softmax(a3 + b4) in place ----
    logsoftmax40<<<(N * 64 + 255) / 256, 256, 0, stream>>>(a3, b4, out, N);
}

// Round 4
// 1230.707 us; speedup vs baseline: 1.7690x; 1.2223x over previous
//
#include <hip/hip_runtime.h>
#include <hip/hip_bf16.h>
#include <cmath>

#define NNODES 100000
#define NEDGES 1600000
#define SCAN_B 1024

typedef __attribute__((ext_vector_type(8))) short bf16x8;
typedef __attribute__((ext_vector_type(4))) float f32x4;

// RNE fp32 -> bf16 (finite inputs)
__device__ __forceinline__ short f2bf(float f) {
    unsigned u = __builtin_bit_cast(unsigned, f);
    unsigned r = (u + 0x7fffu + ((u >> 16) & 1u)) >> 16;
    return (short)r;
}

// ---------------- CSR build ----------------

__global__ void zero_deg(int* __restrict__ deg, int n) {
    int i = blockIdx.x * 256 + threadIdx.x;
    if (i < n) deg[i] = 0;
}

__global__ void count_deg(const int* __restrict__ dst, int* __restrict__ deg, int E) {
    int e = blockIdx.x * 256 + threadIdx.x;
    if (e < E) atomicAdd(&deg[dst[e]], 1);
}

__global__ void calc_dinv(const int* __restrict__ deg, float* __restrict__ dinv, int n) {
    int i = blockIdx.x * 256 + threadIdx.x;
    if (i < n) dinv[i] = rsqrtf(1.0f + (float)deg[i]);   // +1 self-loop
}

__global__ __launch_bounds__(SCAN_B) void scan_block(const int* __restrict__ deg,
                                                     int* __restrict__ pos,
                                                     int* __restrict__ bsums, int n) {
    __shared__ int s[SCAN_B];
    int tid = threadIdx.x;
    int gid = blockIdx.x * SCAN_B + tid;
    int v = (gid < n) ? deg[gid] : 0;
    s[tid] = v;
    __syncthreads();
    for (int off = 1; off < SCAN_B; off <<= 1) {
        int t = (tid >= off) ? s[tid - off] : 0;
        __syncthreads();
        s[tid] += t;
        __syncthreads();
    }
    if (gid < n) pos[gid] = s[tid] - v;          // exclusive
    if (tid == SCAN_B - 1) bsums[blockIdx.x] = s[tid];
}

__global__ __launch_bounds__(128) void scan_sums(int* __restrict__ bsums, int nb) {
    __shared__ int s[128];
    int tid = threadIdx.x;
    int v = (tid < nb) ? bsums[tid] : 0;
    s[tid] = v;
    __syncthreads();
    for (int off = 1; off < 128; off <<= 1) {
        int t = (tid >= off) ? s[tid - off] : 0;
        __syncthreads();
        s[tid] += t;
        __syncthreads();
    }
    if (tid < nb) bsums[tid] = s[tid] - v;       // exclusive
}

__global__ __launch_bounds__(SCAN_B) void add_off(int* __restrict__ pos,
                                                  const int* __restrict__ bsums, int n) {
    int gid = blockIdx.x * SCAN_B + threadIdx.x;
    if (gid < n) pos[gid] += bsums[blockIdx.x];
}

// fill CSR; pos[] is mutated into end[] (end[i-1] == start[i])
__global__ void csr_fill(const int* __restrict__ src, const int* __restrict__ dst,
                         int* __restrict__ pos, int* __restrict__ csr_src, int E) {
    int e = blockIdx.x * 256 + threadIdx.x;
    if (e < E) {
        int slot = atomicAdd(&pos[dst[e]], 1);
        csr_src[slot] = src[e];
    }
}

// ---------------- W1 transpose-convert: W1t[n][k] bf16, k padded 500->512 with zeros ----

__global__ __launch_bounds__(256) void conv_w1t(const float* __restrict__ W1,
                                                short* __restrict__ W1t) {
    int t = blockIdx.x * 256 + threadIdx.x;      // 128*512 threads
    if (t >= 128 * 512) return;
    int n = t >> 9, k = t & 511;
    W1t[t] = (k < 500) ? f2bf(W1[k * 128 + n]) : (short)0;
}

// ---------------- layer-1 MFMA GEMM: h1[M,128] = x[M,500] @ W1[500,128] in bf16 ----------
// Block: 128 rows x 128 cols, 256 threads (4 waves). Wave w: rows [w*32, w*32+32).
// LDS fragment layout [q][128][8] bf16 (q = k-octet) -> conflict-free ds_read_b128.

__global__ __launch_bounds__(256) void gemm1_mfma(
    const float* __restrict__ x, const short* __restrict__ W1t,
    float* __restrict__ C, int M)
{
    __shared__ short sA[4096];   // [4][128][8] bf16 = 8 KB
    __shared__ short sB[4096];   // [4][128][8] bf16 = 8 KB
    const int tid = threadIdx.x;
    const int w = tid >> 6;
    const int l = tid & 63;
    const int lm = l & 15;
    const int q = l >> 4;
    const int row0 = blockIdx.x * 128;

    f32x4 acc[2][8];
    #pragma unroll
    for (int i = 0; i < 2; i++)
        #pragma unroll
        for (int j = 0; j < 8; j++) acc[i][j] = (f32x4){0.f, 0.f, 0.f, 0.f};

    for (int k0 = 0; k0 < 512; k0 += 32) {
        __syncthreads();
        // ---- stage A: fp32 -> bf16, into sA[qq][m][8] ----
        #pragma unroll
        for (int rep = 0; rep < 2; rep++) {
            int b = tid + rep * 256;             // 0..511
            int qq = b >> 7, m = b & 127;
            int r = row0 + m; if (r >= M) r = M - 1;
            int kb = k0 + qq * 8;
            bf16x8 o;
            if (kb + 8 <= 500) {
                float4 u = *(const float4*)(x + (size_t)r * 500 + kb);
                float4 v = *(const float4*)(x + (size_t)r * 500 + kb + 4);
                o[0] = f2bf(u.x); o[1] = f2bf(u.y); o[2] = f2bf(u.z); o[3] = f2bf(u.w);
                o[4] = f2bf(v.x); o[5] = f2bf(v.y); o[6] = f2bf(v.z); o[7] = f2bf(v.w);
            } else {
                #pragma unroll
                for (int j = 0; j < 8; j++) {
                    int k = kb + j;
                    o[j] = (k < 500) ? f2bf(x[(size_t)r * 500 + k]) : (short)0;
                }
            }
            *(bf16x8*)&sA[b * 8] = o;
        }
        // ---- stage B: bf16 copy into sB[qq][n][8] ----
        #pragma unroll
        for (int rep = 0; rep < 2; rep++) {
            int b = tid + rep * 256;
            int qq = b >> 7, n = b & 127;
            bf16x8 v = *(const bf16x8*)(W1t + (size_t)n * 512 + k0 + qq * 8);
            *(bf16x8*)&sB[b * 8] = v;
        }
        __syncthreads();
        // ---- fragments + MFMA ----
        bf16x8 af[2];
        #pragma unroll
        for (int i = 0; i < 2; i++)
            af[i] = *(const bf16x8*)&sA[(q * 128 + w * 32 + i * 16 + lm) * 8];
        bf16x8 bf[8];
        #pragma unroll
        for (int j = 0; j < 8; j++)
            bf[j] = *(const bf16x8*)&sB[(q * 128 + j * 16 + lm) * 8];
        #pragma unroll
        for (int i = 0; i < 2; i++)
            #pragma unroll
            for (int j = 0; j < 8; j++)
                acc[i][j] = __builtin_amdgcn_mfma_f32_16x16x32_bf16(af[i], bf[j], acc[i][j], 0, 0, 0);
    }

    // ---- store: C/D layout col=lane&15, row=(lane>>4)*4+reg ----
    #pragma unroll
    for (int i = 0; i < 2; i++) {
        #pragma unroll
        for (int reg = 0; reg < 4; reg++) {
            int grow = row0 + w * 32 + i * 16 + q * 4 + reg;
            if (grow < M) {
                #pragma unroll
                for (int j = 0; j < 8; j++)
                    C[(size_t)grow * 128 + j * 16 + lm] = acc[i][j][reg];
            }
        }
    }
}

// ---------------- fp32 GEMM (layer 2): C[M,TN] = relu(A+bias)[M,K] @ W[K,TN] ----------------

template<int TN, int KC, bool RELU_BIAS>
__global__ __launch_bounds__(256) void gemm_bias(
    const float* __restrict__ A, const float* __restrict__ W,
    const float* __restrict__ bias, float* __restrict__ C,
    int M, int K)
{
    constexpr int TR = 64;
    constexpr int CPT = TN / 16;
    __shared__ float sA[TR][KC + 1];
    __shared__ float sW[KC][TN];
    const int tx = threadIdx.x & 15;
    const int ty = threadIdx.x >> 4;
    const int row0 = blockIdx.x * TR;

    float acc[4][CPT];
    #pragma unroll
    for (int i = 0; i < 4; i++)
        #pragma unroll
        for (int j = 0; j < CPT; j++) acc[i][j] = 0.0f;

    for (int kc = 0; kc < K; kc += KC) {
        const int kend = (K - kc < KC) ? (K - kc) : KC;
        for (int idx = threadIdx.x; idx < TR * KC; idx += 256) {
            int r = idx / KC, k = idx % KC;
            int row = row0 + r;
            float v = 0.0f;
            if (row < M && k < kend) {
                v = A[(long)row * K + kc + k];
                if (RELU_BIAS) v = fmaxf(v + bias[kc + k], 0.0f);
            }
            sA[r][k] = v;
        }
        for (int idx = threadIdx.x; idx < KC * TN; idx += 256) {
            int k = idx / TN, c = idx % TN;
            sW[k][c] = (k < kend) ? W[(long)(kc + k) * TN + c] : 0.0f;
        }
        __syncthreads();
        #pragma unroll 2
        for (int k = 0; k < KC; ++k) {
            float ar[4];
            #pragma unroll
            for (int i = 0; i < 4; i++) ar[i] = sA[ty + 16 * i][k];
            float wr[CPT];
            #pragma unroll
            for (int j = 0; j < CPT; j++) wr[j] = sW[k][tx + 16 * j];
            #pragma unroll
            for (int i = 0; i < 4; i++)
                #pragma unroll
                for (int j = 0; j < CPT; j++) acc[i][j] += ar[i] * wr[j];
        }
        __syncthreads();
    }
    #pragma unroll
    for (int i = 0; i < 4; i++) {
        int row = row0 + ty + 16 * i;
        if (row < M) {
            #pragma unroll
            for (int j = 0; j < CPT; j++)
                C[(long)row * TN + tx + 16 * j] = acc[i][j];
        }
    }
}

// ---------------- small GEMM for layer 3: K=64, N=40, fused relu(A+b2) ----------------

__global__ __launch_bounds__(256) void gemm_n40(
    const float* __restrict__ A, const float* __restrict__ W,
    const float* __restrict__ bias, float* __restrict__ C, int M)
{
    __shared__ float sA[32][65];
    __shared__ float sW[64][40];
    const int row0 = blockIdx.x * 32;
    for (int idx = threadIdx.x; idx < 64 * 40; idx += 256)
        sW[idx / 40][idx % 40] = W[idx];
    for (int idx = threadIdx.x; idx < 32 * 64; idx += 256) {
        int r = idx >> 6, k = idx & 63;
        int row = row0 + r;
        float v = 0.0f;
        if (row < M) v = fmaxf(A[(long)row * 64 + k] + bias[k], 0.0f);
        sA[r][k] = v;
    }
    __syncthreads();
    float acc[5] = {0, 0, 0, 0, 0};
    int rr[5], cc[5];
    #pragma unroll
    for (int j = 0; j < 5; j++) {
        int o = threadIdx.x + 256 * j;
        rr[j] = o / 40; cc[j] = o % 40;
    }
    for (int k = 0; k < 64; k++) {
        #pragma unroll
        for (int j = 0; j < 5; j++) acc[j] += sA[rr[j]][k] * sW[k][cc[j]];
    }
    #pragma unroll
    for (int j = 0; j < 5; j++) {
        int row = row0 + rr[j];
        if (row < M) C[(long)row * 40 + cc[j]] = acc[j];
    }
}

// ---------------- CSR gather aggregation: out[i] = dinv[i]*(dinv[i]*h[i] + sum dinv[s]*h[s]) ----

template<int F>
__global__ __launch_bounds__(256) void gather_agg(
    const float* __restrict__ h, const float* __restrict__ dinv,
    const int* __restrict__ pos, const int* __restrict__ csr_src,
    float* __restrict__ out, int n)
{
    unsigned t = blockIdx.x * 256u + threadIdx.x;
    unsigned node = t / F;
    unsigned c = t - node * F;
    if (node >= (unsigned)n) return;
    int e0 = node ? pos[node - 1] : 0;
    int e1 = pos[node];
    float di = dinv[node];
    float acc = di * h[(size_t)node * F + c];
    int s = (e0 < e1) ? csr_src[e0] : 0;
    for (int j = e0; j < e1; j++) {
        int snxt = (j + 1 < e1) ? csr_src[j + 1] : 0;
        acc += dinv[s] * h[(size_t)s * F + c];
        s = snxt;
    }
    out[(size_t)node * F + c] = di * acc;
}

// ---------------- log_softmax over rows of 40 (one wave per row), in-place safe ----------------

__global__ __launch_bounds__(256) void logsoftmax40(const float* __restrict__ h,
                                                    const float* __restrict__ bias,
                                                    float* __restrict__ out, int n) {
    int wave = (blockIdx.x * 256 + threadIdx.x) >> 6;
    int lane = threadIdx.x & 63;
    if (wave >= n) return;
    float x = 0.0f, v = -INFINITY;
    if (lane < 40) { x = h[(long)wave * 40 + lane] + bias[lane]; v = x; }
    #pragma unroll
    for (int off = 32; off; off >>= 1) v = fmaxf(v, __shfl_xor(v, off, 64));
    float ex = (lane < 40) ? expf(x - v) : 0.0f;
    float s = ex;
    #pragma unroll
    for (int off = 32; off; off >>= 1) s += __shfl_xor(s, off, 64);
    if (lane < 40) out[(long)wave * 40 + lane] = x - v - logf(s);
}

// ---------------- launch ----------------

extern "C" void kernel_launch(void* const* d_in, const int* in_sizes, int n_in,
                              void* d_out, int out_size, void* d_ws, size_t ws_size,
                              hipStream_t stream) {
    const float* x  = (const float*)d_in[0];
    const int*   ei = (const int*)d_in[1];
    const float* W1 = (const float*)d_in[2];
    const float* b1 = (const float*)d_in[3];
    const float* W2 = (const float*)d_in[4];
    const float* b2 = (const float*)d_in[5];
    const float* W4 = (const float*)d_in[6];
    const float* b4 = (const float*)d_in[7];
    float* out = (float*)d_out;
    float* ws  = (float*)d_ws;

    const int N = NNODES, E = NEDGES;
    const int* src = ei;
    const int* dst = ei + E;

    // workspace layout (floats): ~27.6M floats (~110 MB)
    float* dinv    = ws;                     // 100k
    int*   deg     = (int*)(ws + 100000);
    int*   pos     = (int*)(ws + 200000);
    int*   bsums   = (int*)(ws + 300000);
    int*   csr_src = (int*)(ws + 300200);    // 1.6M ints
    short* W1t     = (short*)(ws + 1900200); // 128*512 bf16 = 32768 floats
    float* P       = ws + 1933000;           // 12.8M region
    float* Q       = ws + 14733000;          // 12.8M region
    float* h1 = P;                           // [N,128]
    float* a1 = Q;                           // [N,128]
    float* h2 = P;                           // [N,64]
    float* a2 = P + 6400000;                 // [N,64]
    float* h3 = Q;                           // [N,40]
    float* a3 = out;                         // [N,40]

    const int nscan = (N + SCAN_B - 1) / SCAN_B;

    // ---- CSR build + norm ----
    zero_deg<<<(N + 255) / 256, 256, 0, stream>>>(deg, N);
    count_deg<<<(E + 255) / 256, 256, 0, stream>>>(dst, deg, E);
    calc_dinv<<<(N + 255) / 256, 256, 0, stream>>>(deg, dinv, N);
    scan_block<<<nscan, SCAN_B, 0, stream>>>(deg, pos, bsums, N);
    scan_sums<<<1, 128, 0, stream>>>(bsums, nscan);
    add_off<<<nscan, SCAN_B, 0, stream>>>(pos, bsums, N);
    csr_fill<<<(E + 255) / 256, 256, 0, stream>>>(src, dst, pos, csr_src, E);

    // ---- weights convert ----
    conv_w1t<<<(128 * 512 + 255) / 256, 256, 0, stream>>>(W1, W1t);

    // ---- layer 1 (bf16 MFMA): h1 = x @ W1 ; a1 = Ahat h1 ----
    gemm1_mfma<<<(N + 127) / 128, 256, 0, stream>>>(x, W1t, h1, N);
    {
        unsigned tot = (unsigned)N * 128u;
        gather_agg<128><<<(tot + 255) / 256, 256, 0, stream>>>(h1, dinv, pos, csr_src, a1, N);
    }

    // ---- layer 2: h2 = relu(a1 + b1) @ W2 ; a2 = Ahat h2 ----
    gemm_bias<64, 64, true><<<(N + 63) / 64, 256, 0, stream>>>(a1, W2, b1, h2, N, 128);
    {
        unsigned tot = (unsigned)N * 64u;
        gather_agg<64><<<(tot + 255) / 256, 256, 0, stream>>>(h2, dinv, pos, csr_src, a2, N);
    }

    // ---- layer 3: h3 = relu(a2 + b2) @ W4 ; a3 = Ahat h3 (into d_out) ----
    gemm_n40<<<(N + 31) / 32, 256, 0, stream>>>(a2, W4, b2, h3, N);
    {
        unsigned tot = (unsigned)N * 40u;
        gather_agg<40><<<(tot + 255) / 256, 256, 0, stream>>>(h3, dinv, pos, csr_src, a3, N);
    }

    // ---- log_softmax(a3 + b4) in place ----
    logsoftmax40<<<(N * 64 + 255) / 256, 256, 0, stream>>>(a3, b4, out, N);
}

// Round 5
// 985.611 us; speedup vs baseline: 2.2089x; 1.2487x over previous
//
#include <hip/hip_runtime.h>
#include <hip/hip_bf16.h>
#include <cmath>

#define NNODES 100000
#define NEDGES 1600000
#define SCAN_B 1024

typedef __attribute__((ext_vector_type(8))) short bf16x8;
typedef __attribute__((ext_vector_type(4))) float f32x4;

// RNE fp32 -> bf16 (finite inputs)
__device__ __forceinline__ unsigned short f2bf(float f) {
    unsigned u = __builtin_bit_cast(unsigned, f);
    unsigned r = (u + 0x7fffu + ((u >> 16) & 1u)) >> 16;
    return (unsigned short)r;
}
__device__ __forceinline__ float bflo(unsigned v) {
    return __builtin_bit_cast(float, v << 16);
}
__device__ __forceinline__ float bfhi(unsigned v) {
    return __builtin_bit_cast(float, v & 0xffff0000u);
}

// ---------------- CSR build ----------------

__global__ void zero_deg(int* __restrict__ deg, int n) {
    int i = blockIdx.x * 256 + threadIdx.x;
    if (i < n) deg[i] = 0;
}

__global__ void count_deg(const int* __restrict__ dst, int* __restrict__ deg, int E) {
    int e = blockIdx.x * 256 + threadIdx.x;
    if (e < E) atomicAdd(&deg[dst[e]], 1);
}

__global__ void calc_dinv(const int* __restrict__ deg, float* __restrict__ dinv, int n) {
    int i = blockIdx.x * 256 + threadIdx.x;
    if (i < n) dinv[i] = rsqrtf(1.0f + (float)deg[i]);   // +1 self-loop
}

__global__ __launch_bounds__(SCAN_B) void scan_block(const int* __restrict__ deg,
                                                     int* __restrict__ pos,
                                                     int* __restrict__ bsums, int n) {
    __shared__ int s[SCAN_B];
    int tid = threadIdx.x;
    int gid = blockIdx.x * SCAN_B + tid;
    int v = (gid < n) ? deg[gid] : 0;
    s[tid] = v;
    __syncthreads();
    for (int off = 1; off < SCAN_B; off <<= 1) {
        int t = (tid >= off) ? s[tid - off] : 0;
        __syncthreads();
        s[tid] += t;
        __syncthreads();
    }
    if (gid < n) pos[gid] = s[tid] - v;          // exclusive
    if (tid == SCAN_B - 1) bsums[blockIdx.x] = s[tid];
}

__global__ __launch_bounds__(128) void scan_sums(int* __restrict__ bsums, int nb) {
    __shared__ int s[128];
    int tid = threadIdx.x;
    int v = (tid < nb) ? bsums[tid] : 0;
    s[tid] = v;
    __syncthreads();
    for (int off = 1; off < 128; off <<= 1) {
        int t = (tid >= off) ? s[tid - off] : 0;
        __syncthreads();
        s[tid] += t;
        __syncthreads();
    }
    if (tid < nb) bsums[tid] = s[tid] - v;       // exclusive
}

__global__ __launch_bounds__(SCAN_B) void add_off(int* __restrict__ pos,
                                                  const int* __restrict__ bsums, int n) {
    int gid = blockIdx.x * SCAN_B + threadIdx.x;
    if (gid < n) pos[gid] += bsums[blockIdx.x];
}

// fill CSR; pos[] is mutated into end[] (end[i-1] == start[i])
__global__ void csr_fill(const int* __restrict__ src, const int* __restrict__ dst,
                         int* __restrict__ pos, int* __restrict__ csr_src, int E) {
    int e = blockIdx.x * 256 + threadIdx.x;
    if (e < E) {
        int slot = atomicAdd(&pos[dst[e]], 1);
        csr_src[slot] = src[e];
    }
}

// ---------------- weight convert: W1t[128][512] bf16 (K padded), W2t[64][128] bf16 ----

__global__ __launch_bounds__(256) void conv_w1t(const float* __restrict__ W1,
                                                unsigned short* __restrict__ W1t) {
    int t = blockIdx.x * 256 + threadIdx.x;      // 128*512
    if (t >= 128 * 512) return;
    int n = t >> 9, k = t & 511;
    W1t[t] = (k < 500) ? f2bf(W1[k * 128 + n]) : (unsigned short)0;
}

__global__ __launch_bounds__(256) void conv_w2t(const float* __restrict__ W2,
                                                unsigned short* __restrict__ W2t) {
    int t = blockIdx.x * 256 + threadIdx.x;      // 64*128
    if (t >= 64 * 128) return;
    int n = t >> 7, k = t & 127;
    W2t[t] = f2bf(W2[k * 64 + n]);
}

// ---------------- layer-1 MFMA GEMM: h1[M,128](bf16) = x[M,500] @ W1 ----------
// Block: 128 rows x 128 cols, 256 threads (4 waves). LDS frag layout [q][row][8].

__global__ __launch_bounds__(256) void gemm1_mfma(
    const float* __restrict__ x, const unsigned short* __restrict__ W1t,
    unsigned short* __restrict__ C, int M)
{
    __shared__ short sA[4096];   // [4][128][8] bf16 = 8 KB
    __shared__ short sB[4096];   // [4][128][8] bf16 = 8 KB
    const int tid = threadIdx.x;
    const int w = tid >> 6;
    const int l = tid & 63;
    const int lm = l & 15;
    const int q = l >> 4;
    const int row0 = blockIdx.x * 128;

    f32x4 acc[2][8];
    #pragma unroll
    for (int i = 0; i < 2; i++)
        #pragma unroll
        for (int j = 0; j < 8; j++) acc[i][j] = (f32x4){0.f, 0.f, 0.f, 0.f};

    for (int k0 = 0; k0 < 512; k0 += 32) {
        __syncthreads();
        #pragma unroll
        for (int rep = 0; rep < 2; rep++) {
            int b = tid + rep * 256;             // 0..511
            int qq = b >> 7, m = b & 127;
            int r = row0 + m; if (r >= M) r = M - 1;
            int kb = k0 + qq * 8;
            bf16x8 o;
            if (kb + 8 <= 500) {
                float4 u = *(const float4*)(x + (size_t)r * 500 + kb);
                float4 v = *(const float4*)(x + (size_t)r * 500 + kb + 4);
                o[0] = f2bf(u.x); o[1] = f2bf(u.y); o[2] = f2bf(u.z); o[3] = f2bf(u.w);
                o[4] = f2bf(v.x); o[5] = f2bf(v.y); o[6] = f2bf(v.z); o[7] = f2bf(v.w);
            } else {
                #pragma unroll
                for (int j = 0; j < 8; j++) {
                    int k = kb + j;
                    o[j] = (k < 500) ? (short)f2bf(x[(size_t)r * 500 + k]) : (short)0;
                }
            }
            *(bf16x8*)&sA[b * 8] = o;
        }
        #pragma unroll
        for (int rep = 0; rep < 2; rep++) {
            int b = tid + rep * 256;
            int qq = b >> 7, n = b & 127;
            bf16x8 v = *(const bf16x8*)(W1t + (size_t)n * 512 + k0 + qq * 8);
            *(bf16x8*)&sB[b * 8] = v;
        }
        __syncthreads();
        bf16x8 af[2];
        #pragma unroll
        for (int i = 0; i < 2; i++)
            af[i] = *(const bf16x8*)&sA[(q * 128 + w * 32 + i * 16 + lm) * 8];
        bf16x8 bfr[8];
        #pragma unroll
        for (int j = 0; j < 8; j++)
            bfr[j] = *(const bf16x8*)&sB[(q * 128 + j * 16 + lm) * 8];
        #pragma unroll
        for (int i = 0; i < 2; i++)
            #pragma unroll
            for (int j = 0; j < 8; j++)
                acc[i][j] = __builtin_amdgcn_mfma_f32_16x16x32_bf16(af[i], bfr[j], acc[i][j], 0, 0, 0);
    }

    // C/D layout: col = j*16 + lm, row = q*4 + reg (+ i*16 + w*32)
    #pragma unroll
    for (int i = 0; i < 2; i++) {
        #pragma unroll
        for (int reg = 0; reg < 4; reg++) {
            int grow = row0 + w * 32 + i * 16 + q * 4 + reg;
            if (grow < M) {
                #pragma unroll
                for (int j = 0; j < 8; j++)
                    C[(size_t)grow * 128 + j * 16 + lm] = f2bf(acc[i][j][reg]);
            }
        }
    }
}

// ---------------- layer-2 MFMA GEMM: h2[M,64](bf16) = a1[M,128](bf16) @ W2 ----------

__global__ __launch_bounds__(256) void gemm2_mfma(
    const unsigned short* __restrict__ A, const unsigned short* __restrict__ Bt,
    unsigned short* __restrict__ C, int M)
{
    __shared__ short sA[4096];   // [4][128][8]
    __shared__ short sB[2048];   // [4][64][8]
    const int tid = threadIdx.x;
    const int w = tid >> 6;
    const int l = tid & 63;
    const int lm = l & 15;
    const int q = l >> 4;
    const int row0 = blockIdx.x * 128;

    f32x4 acc[2][4];
    #pragma unroll
    for (int i = 0; i < 2; i++)
        #pragma unroll
        for (int j = 0; j < 4; j++) acc[i][j] = (f32x4){0.f, 0.f, 0.f, 0.f};

    for (int k0 = 0; k0 < 128; k0 += 32) {
        __syncthreads();
        #pragma unroll
        for (int rep = 0; rep < 2; rep++) {
            int b = tid + rep * 256;             // 0..511
            int qq = b >> 7, m = b & 127;
            int r = row0 + m; if (r >= M) r = M - 1;
            *(bf16x8*)&sA[b * 8] = *(const bf16x8*)(A + (size_t)r * 128 + k0 + qq * 8);
        }
        {
            int b = tid;                         // 0..255
            int qq = b >> 6, n = b & 63;
            *(bf16x8*)&sB[b * 8] = *(const bf16x8*)(Bt + (size_t)n * 128 + k0 + qq * 8);
        }
        __syncthreads();
        bf16x8 af[2];
        #pragma unroll
        for (int i = 0; i < 2; i++)
            af[i] = *(const bf16x8*)&sA[(q * 128 + w * 32 + i * 16 + lm) * 8];
        bf16x8 bfr[4];
        #pragma unroll
        for (int j = 0; j < 4; j++)
            bfr[j] = *(const bf16x8*)&sB[(q * 64 + j * 16 + lm) * 8];
        #pragma unroll
        for (int i = 0; i < 2; i++)
            #pragma unroll
            for (int j = 0; j < 4; j++)
                acc[i][j] = __builtin_amdgcn_mfma_f32_16x16x32_bf16(af[i], bfr[j], acc[i][j], 0, 0, 0);
    }

    #pragma unroll
    for (int i = 0; i < 2; i++) {
        #pragma unroll
        for (int reg = 0; reg < 4; reg++) {
            int grow = row0 + w * 32 + i * 16 + q * 4 + reg;
            if (grow < M) {
                #pragma unroll
                for (int j = 0; j < 4; j++)
                    C[(size_t)grow * 64 + j * 16 + lm] = f2bf(acc[i][j][reg]);
            }
        }
    }
}

// ---------------- small GEMM for layer 3: K=64, N=40, fused relu(A+b2) ----------------

__global__ __launch_bounds__(256) void gemm_n40(
    const float* __restrict__ A, const float* __restrict__ W,
    const float* __restrict__ bias, float* __restrict__ C, int M)
{
    __shared__ float sA[32][65];
    __shared__ float sW[64][40];
    const int row0 = blockIdx.x * 32;
    for (int idx = threadIdx.x; idx < 64 * 40; idx += 256)
        sW[idx / 40][idx % 40] = W[idx];
    for (int idx = threadIdx.x; idx < 32 * 64; idx += 256) {
        int r = idx >> 6, k = idx & 63;
        int row = row0 + r;
        float v = 0.0f;
        if (row < M) v = fmaxf(A[(long)row * 64 + k] + bias[k], 0.0f);
        sA[r][k] = v;
    }
    __syncthreads();
    float acc[5] = {0, 0, 0, 0, 0};
    int rr[5], cc[5];
    #pragma unroll
    for (int j = 0; j < 5; j++) {
        int o = threadIdx.x + 256 * j;
        rr[j] = o / 40; cc[j] = o % 40;
    }
    for (int k = 0; k < 64; k++) {
        #pragma unroll
        for (int j = 0; j < 5; j++) acc[j] += sA[rr[j]][k] * sW[k][cc[j]];
    }
    #pragma unroll
    for (int j = 0; j < 5; j++) {
        int row = row0 + rr[j];
        if (row < M) C[(long)row * 40 + cc[j]] = acc[j];
    }
}

// ---------------- CSR gather aggregation over bf16 h ----------------
// out[i] = dinv[i]*(dinv[i]*h[i] + sum dinv[s]*h[s]); optional fused +bias,relu,->bf16

template<int F, bool OBF16>
__global__ __launch_bounds__(256) void gather_bf(
    const unsigned short* __restrict__ h, const float* __restrict__ dinv,
    const int* __restrict__ pos, const int* __restrict__ csr_src,
    void* __restrict__ outv, const float* __restrict__ bias, int n)
{
    constexpr int P = F / 2;
    unsigned t = blockIdx.x * 256u + threadIdx.x;
    unsigned node = t / P;
    unsigned p = t - node * P;
    if (node >= (unsigned)n) return;
    int e0 = node ? pos[node - 1] : 0;
    int e1 = pos[node];
    float di = dinv[node];
    unsigned sv = *(const unsigned*)(h + (size_t)node * F + 2 * p);
    float a0 = di * bflo(sv);
    float a1 = di * bfhi(sv);
    int s = (e0 < e1) ? csr_src[e0] : 0;
    for (int j = e0; j < e1; j++) {
        int snxt = (j + 1 < e1) ? csr_src[j + 1] : 0;
        float ds = dinv[s];
        unsigned v = *(const unsigned*)(h + (size_t)s * F + 2 * p);
        a0 += ds * bflo(v);
        a1 += ds * bfhi(v);
        s = snxt;
    }
    a0 *= di; a1 *= di;
    if constexpr (OBF16) {
        a0 = fmaxf(a0 + bias[2 * p], 0.0f);
        a1 = fmaxf(a1 + bias[2 * p + 1], 0.0f);
        ((unsigned*)outv)[(size_t)node * P + p] =
            ((unsigned)f2bf(a1) << 16) | (unsigned)f2bf(a0);
    } else {
        float2 r; r.x = a0; r.y = a1;
        ((float2*)outv)[(size_t)node * P + p] = r;
    }
}

// ---------------- fp32 CSR gather for layer 3 (F=40) ----------------

template<int F>
__global__ __launch_bounds__(256) void gather_agg(
    const float* __restrict__ h, const float* __restrict__ dinv,
    const int* __restrict__ pos, const int* __restrict__ csr_src,
    float* __restrict__ out, int n)
{
    unsigned t = blockIdx.x * 256u + threadIdx.x;
    unsigned node = t / F;
    unsigned c = t - node * F;
    if (node >= (unsigned)n) return;
    int e0 = node ? pos[node - 1] : 0;
    int e1 = pos[node];
    float di = dinv[node];
    float acc = di * h[(size_t)node * F + c];
    int s = (e0 < e1) ? csr_src[e0] : 0;
    for (int j = e0; j < e1; j++) {
        int snxt = (j + 1 < e1) ? csr_src[j + 1] : 0;
        acc += dinv[s] * h[(size_t)s * F + c];
        s = snxt;
    }
    out[(size_t)node * F + c] = di * acc;
}

// ---------------- log_softmax over rows of 40 (one wave per row), in-place safe ----------------

__global__ __launch_bounds__(256) void logsoftmax40(const float* __restrict__ h,
                                                    const float* __restrict__ bias,
                                                    float* __restrict__ out, int n) {
    int wave = (blockIdx.x * 256 + threadIdx.x) >> 6;
    int lane = threadIdx.x & 63;
    if (wave >= n) return;
    float x = 0.0f, v = -INFINITY;
    if (lane < 40) { x = h[(long)wave * 40 + lane] + bias[lane]; v = x; }
    #pragma unroll
    for (int off = 32; off; off >>= 1) v = fmaxf(v, __shfl_xor(v, off, 64));
    float ex = (lane < 40) ? expf(x - v) : 0.0f;
    float s = ex;
    #pragma unroll
    for (int off = 32; off; off >>= 1) s += __shfl_xor(s, off, 64);
    if (lane < 40) out[(long)wave * 40 + lane] = x - v - logf(s);
}

// ---------------- launch ----------------

extern "C" void kernel_launch(void* const* d_in, const int* in_sizes, int n_in,
                              void* d_out, int out_size, void* d_ws, size_t ws_size,
                              hipStream_t stream) {
    const float* x  = (const float*)d_in[0];
    const int*   ei = (const int*)d_in[1];
    const float* W1 = (const float*)d_in[2];
    const float* b1 = (const float*)d_in[3];
    const float* W2 = (const float*)d_in[4];
    const float* b2 = (const float*)d_in[5];
    const float* W4 = (const float*)d_in[6];
    const float* b4 = (const float*)d_in[7];
    float* out = (float*)d_out;
    float* ws  = (float*)d_ws;

    const int N = NNODES, E = NEDGES;
    const int* src = ei;
    const int* dst = ei + E;

    // workspace layout (float offsets), with overlay reuse (~85 MB total):
    float*          dinv    = ws;                              // 100k
    int*            deg     = (int*)(ws + 100000);
    int*            pos     = (int*)(ws + 200000);
    int*            bsums   = (int*)(ws + 300000);
    int*            csr_src = (int*)(ws + 300200);             // 1.6M ints
    unsigned short* W1t     = (unsigned short*)(ws + 1900200); // 65536 bf16 = 32768 f
    unsigned short* W2t     = (unsigned short*)(ws + 1933000); // 8192 bf16 = 4096 f
    // region R1 [1937100, 8337100): h1 bf16 [N][128]; later h2 bf16 [N][64]
    unsigned short* h1      = (unsigned short*)(ws + 1937100);
    unsigned short* h2      = (unsigned short*)(ws + 1937100);
    // region R2 [8337100, 14737100): a1 bf16 [N][128]; later h3 fp32 [N][40]
    unsigned short* a1      = (unsigned short*)(ws + 8337100);
    float*          h3      = ws + 8337100;
    // region R3 [14737100, 21137100): a2 fp32 [N][64]
    float*          a2      = ws + 14737100;
    float*          a3      = out;

    const int nscan = (N + SCAN_B - 1) / SCAN_B;

    // ---- CSR build + norm ----
    zero_deg<<<(N + 255) / 256, 256, 0, stream>>>(deg, N);
    count_deg<<<(E + 255) / 256, 256, 0, stream>>>(dst, deg, E);
    calc_dinv<<<(N + 255) / 256, 256, 0, stream>>>(deg, dinv, N);
    scan_block<<<nscan, SCAN_B, 0, stream>>>(deg, pos, bsums, N);
    scan_sums<<<1, 128, 0, stream>>>(bsums, nscan);
    add_off<<<nscan, SCAN_B, 0, stream>>>(pos, bsums, N);
    csr_fill<<<(E + 255) / 256, 256, 0, stream>>>(src, dst, pos, csr_src, E);

    // ---- weights convert ----
    conv_w1t<<<(128 * 512 + 255) / 256, 256, 0, stream>>>(W1, W1t);
    conv_w2t<<<(64 * 128 + 255) / 256, 256, 0, stream>>>(W2, W2t);

    // ---- layer 1: h1(bf16) = x @ W1 ; a1(bf16) = relu(Ahat h1 + b1) ----
    gemm1_mfma<<<(N + 127) / 128, 256, 0, stream>>>(x, W1t, h1, N);
    {
        unsigned tot = (unsigned)N * 64u;   // N * (128/2)
        gather_bf<128, true><<<(tot + 255) / 256, 256, 0, stream>>>(h1, dinv, pos, csr_src, a1, b1, N);
    }

    // ---- layer 2: h2(bf16) = a1 @ W2 ; a2(fp32) = Ahat h2 ----
    gemm2_mfma<<<(N + 127) / 128, 256, 0, stream>>>(a1, W2t, h2, N);
    {
        unsigned tot = (unsigned)N * 32u;   // N * (64/2)
        gather_bf<64, false><<<(tot + 255) / 256, 256, 0, stream>>>(h2, dinv, pos, csr_src, a2, nullptr, N);
    }

    // ---- layer 3 (fp32): h3 = relu(a2 + b2) @ W4 ; a3 = Ahat h3 (into d_out) ----
    gemm_n40<<<(N + 31) / 32, 256, 0, stream>>>(a2, W4, b2, h3, N);
    {
        unsigned tot = (unsigned)N * 40u;
        gather_agg<40><<<(tot + 255) / 256, 256, 0, stream>>>(h3, dinv, pos, csr_src, a3, N);
    }

    // ---- log_softmax(a3 + b4) in place ----
    logsoftmax40<<<(N * 64 + 255) / 256, 256, 0, stream>>>(a3, b4, out, N);
}

// Round 6
// 816.909 us; speedup vs baseline: 2.6651x; 1.2065x over previous
//
#include <hip/hip_runtime.h>
#include <hip/hip_bf16.h>
#include <cmath>

#define NNODES 100000
#define NEDGES 1600000
#define SCAN_B 1024

typedef __attribute__((ext_vector_type(8))) short bf16x8;
typedef __attribute__((ext_vector_type(4))) float f32x4;

// RNE fp32 -> bf16 (finite inputs)
__device__ __forceinline__ unsigned short f2bf(float f) {
    unsigned u = __builtin_bit_cast(unsigned, f);
    unsigned r = (u + 0x7fffu + ((u >> 16) & 1u)) >> 16;
    return (unsigned short)r;
}
__device__ __forceinline__ float bflo(unsigned v) {
    return __builtin_bit_cast(float, v << 16);
}
__device__ __forceinline__ float bfhi(unsigned v) {
    return __builtin_bit_cast(float, v & 0xffff0000u);
}

// ---------------- CSR build ----------------

__global__ void zero_deg(int* __restrict__ deg, int n) {
    int i = blockIdx.x * 256 + threadIdx.x;
    if (i < n) deg[i] = 0;
}

__global__ void count_deg(const int* __restrict__ dst, int* __restrict__ deg, int E) {
    int e = blockIdx.x * 256 + threadIdx.x;
    if (e < E) atomicAdd(&deg[dst[e]], 1);
}

__global__ void calc_dinv(const int* __restrict__ deg, float* __restrict__ dinv, int n) {
    int i = blockIdx.x * 256 + threadIdx.x;
    if (i < n) dinv[i] = rsqrtf(1.0f + (float)deg[i]);   // +1 self-loop
}

__global__ __launch_bounds__(SCAN_B) void scan_block(const int* __restrict__ deg,
                                                     int* __restrict__ pos,
                                                     int* __restrict__ bsums, int n) {
    __shared__ int s[SCAN_B];
    int tid = threadIdx.x;
    int gid = blockIdx.x * SCAN_B + tid;
    int v = (gid < n) ? deg[gid] : 0;
    s[tid] = v;
    __syncthreads();
    for (int off = 1; off < SCAN_B; off <<= 1) {
        int t = (tid >= off) ? s[tid - off] : 0;
        __syncthreads();
        s[tid] += t;
        __syncthreads();
    }
    if (gid < n) pos[gid] = s[tid] - v;          // exclusive
    if (tid == SCAN_B - 1) bsums[blockIdx.x] = s[tid];
}

__global__ __launch_bounds__(128) void scan_sums(int* __restrict__ bsums, int nb) {
    __shared__ int s[128];
    int tid = threadIdx.x;
    int v = (tid < nb) ? bsums[tid] : 0;
    s[tid] = v;
    __syncthreads();
    for (int off = 1; off < 128; off <<= 1) {
        int t = (tid >= off) ? s[tid - off] : 0;
        __syncthreads();
        s[tid] += t;
        __syncthreads();
    }
    if (tid < nb) bsums[tid] = s[tid] - v;       // exclusive
}

__global__ __launch_bounds__(SCAN_B) void add_off(int* __restrict__ pos,
                                                  const int* __restrict__ bsums, int n) {
    int gid = blockIdx.x * SCAN_B + threadIdx.x;
    if (gid < n) pos[gid] += bsums[blockIdx.x];
}

// fill CSR; pos[] is mutated into end[] (end[i-1] == start[i])
__global__ void csr_fill(const int* __restrict__ src, const int* __restrict__ dst,
                         int* __restrict__ pos, int* __restrict__ csr_src, int E) {
    int e = blockIdx.x * 256 + threadIdx.x;
    if (e < E) {
        int slot = atomicAdd(&pos[dst[e]], 1);
        csr_src[slot] = src[e];
    }
}

// ---------------- weight convert ----------------

__global__ __launch_bounds__(256) void conv_w1t(const float* __restrict__ W1,
                                                unsigned short* __restrict__ W1t) {
    int t = blockIdx.x * 256 + threadIdx.x;      // 128*512
    if (t >= 128 * 512) return;
    int n = t >> 9, k = t & 511;
    W1t[t] = (k < 500) ? f2bf(W1[k * 128 + n]) : (unsigned short)0;
}

__global__ __launch_bounds__(256) void conv_w2t(const float* __restrict__ W2,
                                                unsigned short* __restrict__ W2t) {
    int t = blockIdx.x * 256 + threadIdx.x;      // 64*128
    if (t >= 64 * 128) return;
    int n = t >> 7, k = t & 127;
    W2t[t] = f2bf(W2[k * 64 + n]);
}

// ---------------- layer-1 MFMA GEMM: h1'[M,128](bf16) = dinv .* (x @ W1) ----------

__global__ __launch_bounds__(256) void gemm1_mfma(
    const float* __restrict__ x, const unsigned short* __restrict__ W1t,
    const float* __restrict__ dinv, unsigned short* __restrict__ C, int M)
{
    __shared__ short sA[4096];   // [4][128][8]
    __shared__ short sB[4096];
    const int tid = threadIdx.x;
    const int w = tid >> 6;
    const int l = tid & 63;
    const int lm = l & 15;
    const int q = l >> 4;
    const int row0 = blockIdx.x * 128;

    f32x4 acc[2][8];
    #pragma unroll
    for (int i = 0; i < 2; i++)
        #pragma unroll
        for (int j = 0; j < 8; j++) acc[i][j] = (f32x4){0.f, 0.f, 0.f, 0.f};

    for (int k0 = 0; k0 < 512; k0 += 32) {
        __syncthreads();
        #pragma unroll
        for (int rep = 0; rep < 2; rep++) {
            int b = tid + rep * 256;             // 0..511
            int qq = b >> 7, m = b & 127;
            int r = row0 + m; if (r >= M) r = M - 1;
            int kb = k0 + qq * 8;
            bf16x8 o;
            if (kb + 8 <= 500) {
                float4 u = *(const float4*)(x + (size_t)r * 500 + kb);
                float4 v = *(const float4*)(x + (size_t)r * 500 + kb + 4);
                o[0] = f2bf(u.x); o[1] = f2bf(u.y); o[2] = f2bf(u.z); o[3] = f2bf(u.w);
                o[4] = f2bf(v.x); o[5] = f2bf(v.y); o[6] = f2bf(v.z); o[7] = f2bf(v.w);
            } else {
                #pragma unroll
                for (int j = 0; j < 8; j++) {
                    int k = kb + j;
                    o[j] = (k < 500) ? (short)f2bf(x[(size_t)r * 500 + k]) : (short)0;
                }
            }
            *(bf16x8*)&sA[b * 8] = o;
        }
        #pragma unroll
        for (int rep = 0; rep < 2; rep++) {
            int b = tid + rep * 256;
            int qq = b >> 7, n = b & 127;
            bf16x8 v = *(const bf16x8*)(W1t + (size_t)n * 512 + k0 + qq * 8);
            *(bf16x8*)&sB[b * 8] = v;
        }
        __syncthreads();
        bf16x8 af[2];
        #pragma unroll
        for (int i = 0; i < 2; i++)
            af[i] = *(const bf16x8*)&sA[(q * 128 + w * 32 + i * 16 + lm) * 8];
        bf16x8 bfr[8];
        #pragma unroll
        for (int j = 0; j < 8; j++)
            bfr[j] = *(const bf16x8*)&sB[(q * 128 + j * 16 + lm) * 8];
        #pragma unroll
        for (int i = 0; i < 2; i++)
            #pragma unroll
            for (int j = 0; j < 8; j++)
                acc[i][j] = __builtin_amdgcn_mfma_f32_16x16x32_bf16(af[i], bfr[j], acc[i][j], 0, 0, 0);
    }

    // C/D layout: col = j*16 + lm, row = q*4 + reg (+ i*16 + w*32); pre-scale by dinv[row]
    #pragma unroll
    for (int i = 0; i < 2; i++) {
        #pragma unroll
        for (int reg = 0; reg < 4; reg++) {
            int grow = row0 + w * 32 + i * 16 + q * 4 + reg;
            if (grow < M) {
                float d = dinv[grow];
                #pragma unroll
                for (int j = 0; j < 8; j++)
                    C[(size_t)grow * 128 + j * 16 + lm] = f2bf(d * acc[i][j][reg]);
            }
        }
    }
}

// ---------------- layer-2 MFMA GEMM: h2'[M,64](bf16) = dinv .* (a1 @ W2) ----------

__global__ __launch_bounds__(256) void gemm2_mfma(
    const unsigned short* __restrict__ A, const unsigned short* __restrict__ Bt,
    const float* __restrict__ dinv, unsigned short* __restrict__ C, int M)
{
    __shared__ short sA[4096];
    __shared__ short sB[2048];
    const int tid = threadIdx.x;
    const int w = tid >> 6;
    const int l = tid & 63;
    const int lm = l & 15;
    const int q = l >> 4;
    const int row0 = blockIdx.x * 128;

    f32x4 acc[2][4];
    #pragma unroll
    for (int i = 0; i < 2; i++)
        #pragma unroll
        for (int j = 0; j < 4; j++) acc[i][j] = (f32x4){0.f, 0.f, 0.f, 0.f};

    for (int k0 = 0; k0 < 128; k0 += 32) {
        __syncthreads();
        #pragma unroll
        for (int rep = 0; rep < 2; rep++) {
            int b = tid + rep * 256;
            int qq = b >> 7, m = b & 127;
            int r = row0 + m; if (r >= M) r = M - 1;
            *(bf16x8*)&sA[b * 8] = *(const bf16x8*)(A + (size_t)r * 128 + k0 + qq * 8);
        }
        {
            int b = tid;
            int qq = b >> 6, n = b & 63;
            *(bf16x8*)&sB[b * 8] = *(const bf16x8*)(Bt + (size_t)n * 128 + k0 + qq * 8);
        }
        __syncthreads();
        bf16x8 af[2];
        #pragma unroll
        for (int i = 0; i < 2; i++)
            af[i] = *(const bf16x8*)&sA[(q * 128 + w * 32 + i * 16 + lm) * 8];
        bf16x8 bfr[4];
        #pragma unroll
        for (int j = 0; j < 4; j++)
            bfr[j] = *(const bf16x8*)&sB[(q * 64 + j * 16 + lm) * 8];
        #pragma unroll
        for (int i = 0; i < 2; i++)
            #pragma unroll
            for (int j = 0; j < 4; j++)
                acc[i][j] = __builtin_amdgcn_mfma_f32_16x16x32_bf16(af[i], bfr[j], acc[i][j], 0, 0, 0);
    }

    #pragma unroll
    for (int i = 0; i < 2; i++) {
        #pragma unroll
        for (int reg = 0; reg < 4; reg++) {
            int grow = row0 + w * 32 + i * 16 + q * 4 + reg;
            if (grow < M) {
                float d = dinv[grow];
                #pragma unroll
                for (int j = 0; j < 4; j++)
                    C[(size_t)grow * 64 + j * 16 + lm] = f2bf(d * acc[i][j][reg]);
            }
        }
    }
}

// ---------------- layer-3 GEMM: h3'[M,40](fp32) = dinv .* (relu(A+b2) @ W4) ----------------

__global__ __launch_bounds__(256) void gemm_n40(
    const float* __restrict__ A, const float* __restrict__ W,
    const float* __restrict__ bias, const float* __restrict__ dinv,
    float* __restrict__ C, int M)
{
    __shared__ float sA[32][65];
    __shared__ float sW[64][40];
    const int row0 = blockIdx.x * 32;
    for (int idx = threadIdx.x; idx < 64 * 40; idx += 256)
        sW[idx / 40][idx % 40] = W[idx];
    for (int idx = threadIdx.x; idx < 32 * 64; idx += 256) {
        int r = idx >> 6, k = idx & 63;
        int row = row0 + r;
        float v = 0.0f;
        if (row < M) v = fmaxf(A[(long)row * 64 + k] + bias[k], 0.0f);
        sA[r][k] = v;
    }
    __syncthreads();
    float acc[5] = {0, 0, 0, 0, 0};
    int rr[5], cc[5];
    #pragma unroll
    for (int j = 0; j < 5; j++) {
        int o = threadIdx.x + 256 * j;
        rr[j] = o / 40; cc[j] = o % 40;
    }
    for (int k = 0; k < 64; k++) {
        #pragma unroll
        for (int j = 0; j < 5; j++) acc[j] += sA[rr[j]][k] * sW[k][cc[j]];
    }
    #pragma unroll
    for (int j = 0; j < 5; j++) {
        int row = row0 + rr[j];
        if (row < M) C[(long)row * 40 + cc[j]] = dinv[row] * acc[j];
    }
}

// ---------------- CSR gather over pre-scaled bf16 h': out[i] = di*(h'[i] + sum h'[s]) ----
// optional fused +bias,relu,->bf16 epilogue

template<int F, bool OBF16>
__global__ __launch_bounds__(256) void gather_bf(
    const unsigned short* __restrict__ h, const float* __restrict__ dinv,
    const int* __restrict__ pos, const int* __restrict__ csr_src,
    void* __restrict__ outv, const float* __restrict__ bias, int n)
{
    constexpr int P = F / 2;
    unsigned t = blockIdx.x * 256u + threadIdx.x;
    unsigned node = t / P;
    unsigned p = t - node * P;
    if (node >= (unsigned)n) return;
    int e0 = node ? pos[node - 1] : 0;
    int e1 = pos[node];
    float di = dinv[node];
    unsigned sv = *(const unsigned*)(h + (size_t)node * F + 2 * p);
    float a0 = bflo(sv);
    float a1 = bfhi(sv);
    int j = e0;
    for (; j + 4 <= e1; j += 4) {
        int s0 = csr_src[j], s1 = csr_src[j + 1], s2 = csr_src[j + 2], s3 = csr_src[j + 3];
        unsigned v0 = *(const unsigned*)(h + (size_t)s0 * F + 2 * p);
        unsigned v1 = *(const unsigned*)(h + (size_t)s1 * F + 2 * p);
        unsigned v2 = *(const unsigned*)(h + (size_t)s2 * F + 2 * p);
        unsigned v3 = *(const unsigned*)(h + (size_t)s3 * F + 2 * p);
        a0 += bflo(v0) + bflo(v1) + bflo(v2) + bflo(v3);
        a1 += bfhi(v0) + bfhi(v1) + bfhi(v2) + bfhi(v3);
    }
    for (; j < e1; j++) {
        int s = csr_src[j];
        unsigned v = *(const unsigned*)(h + (size_t)s * F + 2 * p);
        a0 += bflo(v);
        a1 += bfhi(v);
    }
    a0 *= di; a1 *= di;
    if constexpr (OBF16) {
        a0 = fmaxf(a0 + bias[2 * p], 0.0f);
        a1 = fmaxf(a1 + bias[2 * p + 1], 0.0f);
        ((unsigned*)outv)[(size_t)node * P + p] =
            ((unsigned)f2bf(a1) << 16) | (unsigned)f2bf(a0);
    } else {
        float2 r; r.x = a0; r.y = a1;
        ((float2*)outv)[(size_t)node * P + p] = r;
    }
}

// ---------------- fp32 CSR gather over pre-scaled h' (layer 3, F=40) ----------------

template<int F>
__global__ __launch_bounds__(256) void gather_agg(
    const float* __restrict__ h, const float* __restrict__ dinv,
    const int* __restrict__ pos, const int* __restrict__ csr_src,
    float* __restrict__ out, int n)
{
    unsigned t = blockIdx.x * 256u + threadIdx.x;
    unsigned node = t / F;
    unsigned c = t - node * F;
    if (node >= (unsigned)n) return;
    int e0 = node ? pos[node - 1] : 0;
    int e1 = pos[node];
    float di = dinv[node];
    float acc = h[(size_t)node * F + c];
    int j = e0;
    for (; j + 4 <= e1; j += 4) {
        int s0 = csr_src[j], s1 = csr_src[j + 1], s2 = csr_src[j + 2], s3 = csr_src[j + 3];
        float v0 = h[(size_t)s0 * F + c];
        float v1 = h[(size_t)s1 * F + c];
        float v2 = h[(size_t)s2 * F + c];
        float v3 = h[(size_t)s3 * F + c];
        acc += v0 + v1 + v2 + v3;
    }
    for (; j < e1; j++) {
        int s = csr_src[j];
        acc += h[(size_t)s * F + c];
    }
    out[(size_t)node * F + c] = di * acc;
}

// ---------------- log_softmax over rows of 40 (one wave per row), in-place safe ----------------

__global__ __launch_bounds__(256) void logsoftmax40(const float* __restrict__ h,
                                                    const float* __restrict__ bias,
                                                    float* __restrict__ out, int n) {
    int wave = (blockIdx.x * 256 + threadIdx.x) >> 6;
    int lane = threadIdx.x & 63;
    if (wave >= n) return;
    float x = 0.0f, v = -INFINITY;
    if (lane < 40) { x = h[(long)wave * 40 + lane] + bias[lane]; v = x; }
    #pragma unroll
    for (int off = 32; off; off >>= 1) v = fmaxf(v, __shfl_xor(v, off, 64));
    float ex = (lane < 40) ? expf(x - v) : 0.0f;
    float s = ex;
    #pragma unroll
    for (int off = 32; off; off >>= 1) s += __shfl_xor(s, off, 64);
    if (lane < 40) out[(long)wave * 40 + lane] = x - v - logf(s);
}

// ---------------- launch ----------------

extern "C" void kernel_launch(void* const* d_in, const int* in_sizes, int n_in,
                              void* d_out, int out_size, void* d_ws, size_t ws_size,
                              hipStream_t stream) {
    const float* x  = (const float*)d_in[0];
    const int*   ei = (const int*)d_in[1];
    const float* W1 = (const float*)d_in[2];
    const float* b1 = (const float*)d_in[3];
    const float* W2 = (const float*)d_in[4];
    const float* b2 = (const float*)d_in[5];
    const float* W4 = (const float*)d_in[6];
    const float* b4 = (const float*)d_in[7];
    float* out = (float*)d_out;
    float* ws  = (float*)d_ws;

    const int N = NNODES, E = NEDGES;
    const int* src = ei;
    const int* dst = ei + E;

    // workspace layout (float offsets), with overlay reuse (~85 MB total):
    float*          dinv    = ws;                              // 100k
    int*            deg     = (int*)(ws + 100000);
    int*            pos     = (int*)(ws + 200000);
    int*            bsums   = (int*)(ws + 300000);
    int*            csr_src = (int*)(ws + 300200);             // 1.6M ints
    unsigned short* W1t     = (unsigned short*)(ws + 1900200);
    unsigned short* W2t     = (unsigned short*)(ws + 1933000);
    // region R1: h1' bf16 [N][128]; later h2' bf16 [N][64]
    unsigned short* h1      = (unsigned short*)(ws + 1937100);
    unsigned short* h2      = (unsigned short*)(ws + 1937100);
    // region R2: a1 bf16 [N][128]; later h3' fp32 [N][40]
    unsigned short* a1      = (unsigned short*)(ws + 8337100);
    float*          h3      = ws + 8337100;
    // region R3: a2 fp32 [N][64]
    float*          a2      = ws + 14737100;
    float*          a3      = out;

    const int nscan = (N + SCAN_B - 1) / SCAN_B;

    // ---- CSR build + norm ----
    zero_deg<<<(N + 255) / 256, 256, 0, stream>>>(deg, N);
    count_deg<<<(E + 255) / 256, 256, 0, stream>>>(dst, deg, E);
    calc_dinv<<<(N + 255) / 256, 256, 0, stream>>>(deg, dinv, N);
    scan_block<<<nscan, SCAN_B, 0, stream>>>(deg, pos, bsums, N);
    scan_sums<<<1, 128, 0, stream>>>(bsums, nscan);
    add_off<<<nscan, SCAN_B, 0, stream>>>(pos, bsums, N);
    csr_fill<<<(E + 255) / 256, 256, 0, stream>>>(src, dst, pos, csr_src, E);

    // ---- weights convert ----
    conv_w1t<<<(128 * 512 + 255) / 256, 256, 0, stream>>>(W1, W1t);
    conv_w2t<<<(64 * 128 + 255) / 256, 256, 0, stream>>>(W2, W2t);

    // ---- layer 1: h1' = dinv.*(x @ W1) ; a1(bf16) = relu(di*(h1'[i]+sum h1'[s]) + b1) ----
    gemm1_mfma<<<(N + 127) / 128, 256, 0, stream>>>(x, W1t, dinv, h1, N);
    {
        unsigned tot = (unsigned)N * 64u;
        gather_bf<128, true><<<(tot + 255) / 256, 256, 0, stream>>>(h1, dinv, pos, csr_src, a1, b1, N);
    }

    // ---- layer 2: h2' = dinv.*(a1 @ W2) ; a2(fp32) = di*(h2'[i]+sum h2'[s]) ----
    gemm2_mfma<<<(N + 127) / 128, 256, 0, stream>>>(a1, W2t, dinv, h2, N);
    {
        unsigned tot = (unsigned)N * 32u;
        gather_bf<64, false><<<(tot + 255) / 256, 256, 0, stream>>>(h2, dinv, pos, csr_src, a2, nullptr, N);
    }

    // ---- layer 3: h3' = dinv.*(relu(a2+b2) @ W4) ; a3 = di*(h3'[i]+sum h3'[s]) ----
    gemm_n40<<<(N + 31) / 32, 256, 0, stream>>>(a2, W4, b2, dinv, h3, N);
    {
        unsigned tot = (unsigned)N * 40u;
        gather_agg<40><<<(tot + 255) / 256, 256, 0, stream>>>(h3, dinv, pos, csr_src, a3, N);
    }

    // ---- log_softmax(a3 + b4) in place ----
    logsoftmax40<<<(N * 64 + 255) / 256, 256, 0, stream>>>(a3, b4, out, N);
}